// Round 6
// baseline (317.179 us; speedup 1.0000x reference)
//
#include <hip/hip_runtime.h>
#include <hip/hip_bf16.h>

// FlowNetC correlation via bf16 MFMA band-GEMM.
// out[b, (dy+4)*9+(dx+4), y, x] = (1/256) * sum_c in1[b,c,y,x] * in2[b,c,y+dy,x+dx]
// B=8, C=256, H=96, W=128, MD=4.
//
// v7: two-kernel scheme attacking cache-line fill latency (the ~8k unexplained
// cycles/chunk/CU at <8% pipe utilization in v4-v6):
//  - prep: fp32 NCHW -> bf16 chunk-plane pixel-run layout in d_ws
//    (ws[img][b][kc][y][x] = 64 B run of 32 ch, group order permuted by the
//    LDS bank swizzle F(x), which provably depends only on global x).
//    Halves all main-kernel fetch bytes/lines. Also writes a 1 KB zero page.
//  - corr_mfma7: staging is pure global_load_lds DMA (5 wave-ops per chunk
//    per wave, no VGPR round-trip, no cvt, no ds_write). OOB halo lanes point
//    at the zero page instead of exec-masking, so vmcnt counts are exact.
//    Counted s_waitcnt vmcnt(5) keeps next chunk's DMAs in flight across both
//    barriers; global_load_lds cannot be sunk by the register allocator
//    (v6's failure mode). Register pressure drops -> __launch_bounds__(512,4)
//    targets the 128-reg tier = 2 blocks/CU (LDS 2x80 KB = 160 KB exact).
// Compute + epilogue are byte-identical to v5/v6 (verified).
// Fallback to the proven v6 monolithic kernel if ws_size is too small.

#define B_ 8
#define C_ 256
#define H_ 96
#define W_ 128
#define HW_ 12288
#define CHW_ 3145728

#define BUFSZ 40960
#define IN1_OFF 0            // in1: 8*16 = 128 slots
#define IN2_OFF 8192         // in2: 16*32 = 512 slots
#define IN2_ROWB (32 * 64)   // bytes per in2 LDS row

#define PLANEB 786432        // 12288 px * 64 B per chunk-plane
#define IMGWS  50331648      // 8 b * 8 kc * PLANEB
#define WS_NEED (2ull * IMGWS + 1024ull)

typedef __attribute__((ext_vector_type(8))) short short8;
typedef __attribute__((ext_vector_type(4))) float f32x4;

// bank swizzle on the 16B channel-group within a 64B pixel slot
__device__ __forceinline__ int swz16(int g, int slot) {
    return (g ^ (slot & 3) ^ ((slot >> 2) & 3)) * 16;
}

__device__ __forceinline__ void gload16(const void* g, void* l) {
    __builtin_amdgcn_global_load_lds(
        (const __attribute__((address_space(1))) unsigned int*)g,
        (__attribute__((address_space(3))) unsigned int*)l, 16, 0, 0);
}

// ---------------------------------------------------------------------------
// prep: NCHW fp32 -> chunk-plane pixel-run bf16 with baked swizzle permutation
// grid 1536 x 256: blocks 0..767 = in1 (img 0), 768..1535 = in2 (img 1);
// block = (img, b, kc, y-oct). Thread (g=tid&3, xq=(tid>>2)&15, yl=tid>>6)
// copies 4 px x 8 ch per inner step; reads coalesced 256 B runs, writes 16 B
// aligned chunks of 64 B pixel runs.
// ---------------------------------------------------------------------------
__global__ __launch_bounds__(256) void prep(
    const float* __restrict__ in1,
    const float* __restrict__ in2,
    char* __restrict__ ws)
{
    const int blk = blockIdx.x;
    const int tid = threadIdx.x;

    if (blk == 0)   // zero page for OOB halo staging
        *(float*)(ws + 2 * (size_t)IMGWS + tid * 4) = 0.f;

    const int img  = (blk >= 768) ? 1 : 0;
    const int r    = blk - img * 768;
    const int b    = r & 7;
    const int rest = r >> 3;          // 0..95
    const int kc   = rest & 7;
    const int yo   = rest >> 3;       // 0..11

    const float* src = (img ? in2 : in1) + (size_t)b * CHW_ + (size_t)(kc * 32) * HW_;
    char* dplane = ws + (size_t)img * IMGWS + (size_t)(b * 8 + kc) * PLANEB;

    const int g  = tid & 3;
    const int xq = (tid >> 2) & 15;
    const int yl = tid >> 6;          // 0..3

    #pragma unroll
    for (int yi = 0; yi < 2; ++yi) {
        const int y = yo * 8 + yi * 4 + yl;
        #pragma unroll
        for (int x2 = 0; x2 < 2; ++x2) {
            const int px0 = x2 * 64 + xq * 4;
            f32x4 v[8];
            #pragma unroll
            for (int jj = 0; jj < 8; ++jj)
                v[jj] = *(const f32x4*)(src + (size_t)(8 * g + jj) * HW_ + y * W_ + px0);
            #pragma unroll
            for (int j = 0; j < 4; ++j) {
                const int px = px0 + j;
                union { __hip_bfloat162 h2[4]; short8 s8; } u;
                #pragma unroll
                for (int p = 0; p < 4; ++p)
                    u.h2[p] = __float22bfloat162_rn(float2{v[2 * p][j], v[2 * p + 1][j]});
                // baked LDS swizzle: in2 slots sit at px+8 within rows, in1 at px
                const int F = img ? ((px & 3) ^ (((px + 8) >> 2) & 3))
                                  : ((px & 3) ^ ((px >> 2) & 3));
                *(short8*)(dplane + ((size_t)y * W_ + px) * 64 + (g ^ F) * 16) = u.s8;
            }
        }
    }
}

// ---------------------------------------------------------------------------
// main: DMA-staged band-GEMM
// ---------------------------------------------------------------------------
__global__ __launch_bounds__(512, 4) void corr_mfma7(
    const char* __restrict__ ws,
    float* __restrict__ out)
{
    __shared__ __align__(16) char lds[2 * BUFSZ];

    const int tid = threadIdx.x;
    const int blk = blockIdx.x;
    const int b    = blk & 7;         // XCD pinning: one batch per XCD
    const int rest = blk >> 3;        // 0..95
    const int yt   = rest >> 3;       // 0..11 (8-row tiles)
    const int xh   = rest & 7;        // 0..7  (16-px eighths)

    const int lane = tid & 63;
    const int wv   = tid >> 6;        // 0..7
    const int ut   = wv & 1;
    const int yrh  = wv >> 1;         // 0..3 -> y rows 2*yrh, 2*yrh+1
    const int ln   = lane & 15;
    const int qd   = lane >> 4;

    const int offA0 = IN1_OFF + ((2 * yrh) * 16 + ln) * 64 + swz16(qd, ln);
    const int pB    = 16 * ut + ln;
    const int offB  = IN2_OFF + ((2 * yrh) * 32 + pB) * 64 + swz16(qd, pB);

    const char* ws1 = ws;
    const char* ws2 = ws + (size_t)IMGWS;
    const char* zp  = ws + 2 * (size_t)IMGWS + (lane & 3) * 16;
    const int b8 = b * 8;

    const int plx   = lane >> 2;       // px within a 16-px staging segment
    const int pos16 = (lane & 3) * 16; // channel-group position within run

    f32x4 acc0[9], acc1[9];
    #pragma unroll
    for (int s = 0; s < 9; ++s) { acc0[s] = f32x4{0.f,0.f,0.f,0.f}; acc1[s] = f32x4{0.f,0.f,0.f,0.f}; }

    // issue: 40 DMA segments per chunk (in2: 16 rows x 2 segs, in1: 8 rows),
    // 5 per wave. Exactly 5 vmem ops issued per wave regardless of masking
    // (OOB lanes read the zero page), so vmcnt counts are exact.
    auto issue = [&](int kc, char* buf) {
        const char* p2 = ws2 + (size_t)(b8 + kc) * PLANEB;
        const char* p1 = ws1 + (size_t)(b8 + kc) * PLANEB;
        #pragma unroll
        for (int i = 0; i < 5; ++i) {
            const int id = wv * 5 + i;
            if (id < 32) {
                const int row = id >> 1, seg = id & 1;
                const int gy = yt * 8 - 4 + row;
                const int gx = xh * 16 - 8 + seg * 16 + plx;
                const bool vld = (gy >= 0) && (gy < H_) && (gx >= 0) && (gx < W_);
                const char* src = vld ? (p2 + (((size_t)gy << 7) + gx) * 64 + pos16) : zp;
                gload16(src, buf + IN2_OFF + ((row * 32 + seg * 16) << 6));
            } else {
                const int row = id - 32;
                const int gy = yt * 8 + row;
                const int gx = xh * 16 + plx;
                const char* src = p1 + (((size_t)gy << 7) + gx) * 64 + pos16;
                gload16(src, buf + IN1_OFF + (row << 10));
            }
        }
    };

    auto compute = [&](const char* __restrict__ buf) {
        short8 a0  = *(const short8*)(buf + offA0);
        short8 a1  = *(const short8*)(buf + offA0 + 16 * 64);
        short8 blo = *(const short8*)(buf + offB);
        #pragma unroll
        for (int s = 0; s < 9; ++s) {
            short8 bhi = *(const short8*)(buf + offB + (s + 1) * IN2_ROWB);
            acc0[s] = __builtin_amdgcn_mfma_f32_16x16x32_bf16(a0, blo, acc0[s], 0, 0, 0);
            acc1[s] = __builtin_amdgcn_mfma_f32_16x16x32_bf16(a1, bhi, acc1[s], 0, 0, 0);
            blo = bhi;
        }
    };

    // no LDS zero-fill needed: every slot is DMA-written every chunk
    issue(0, lds);
    issue(1, lds + BUFSZ);

    #pragma unroll
    for (int kc = 0; kc < 8; ++kc) {
        char* buf = lds + (kc & 1) * BUFSZ;
        if (kc < 7) { asm volatile("s_waitcnt vmcnt(5)" ::: "memory"); }
        else        { asm volatile("s_waitcnt vmcnt(0)" ::: "memory"); }
        __builtin_amdgcn_s_barrier();          // all waves' chunk-kc DMAs landed
        compute(buf);
        __builtin_amdgcn_s_barrier();          // all waves done reading buf
        if (kc + 2 < 8) issue(kc + 2, buf);    // DMA flies across next barriers
    }

    // ---------------- epilogue: LDS-transposed coalesced band extraction ----
    const float scale = 1.0f / 256.0f;
    float* outb = out + (size_t)b * 81 * HW_ + (size_t)(yt * 8) * W_ + xh * 16;

    #pragma unroll
    for (int s = 0; s < 9; ++s) {
        #pragma unroll
        for (int yr = 0; yr < 2; ++yr) {
            const f32x4 a = yr ? acc1[s] : acc0[s];
            const int y = 2 * yrh + yr;
            #pragma unroll
            for (int r = 0; r < 4; ++r) {
                const int m  = qd * 4 + r;
                const int dx = ln - m - 8 + 16 * ut;
                if (dx >= -4 && dx <= 4)
                    *(float*)(lds + ((y * 9 + dx + 4) * 16 + m) * 4) = a[r] * scale;
            }
        }
        asm volatile("s_waitcnt lgkmcnt(0)" ::: "memory");
        __builtin_amdgcn_s_barrier();
        asm volatile("" ::: "memory");
        #pragma unroll
        for (int i = 0; i < 3; ++i) {
            const int pidx = i * 4 + qd;
            if (pidx < 9) {
                const float v = *(const float*)(lds + ((wv * 9 + pidx) * 16 + ln) * 4);
                outb[((size_t)(s * 9 + pidx) * H_ + wv) * W_ + ln] = v;
            }
        }
        asm volatile("s_waitcnt lgkmcnt(0)" ::: "memory");
        __builtin_amdgcn_s_barrier();
        asm volatile("" ::: "memory");
    }
}

// ---------------------------------------------------------------------------
// fallback: proven v6 kernel (used only if ws_size < WS_NEED)
// ---------------------------------------------------------------------------
__global__ __launch_bounds__(512, 2) void corr_fb(
    const float* __restrict__ in1,
    const float* __restrict__ in2,
    float* __restrict__ out)
{
    __shared__ __align__(16) char lds[2 * BUFSZ];
    const int tid = threadIdx.x;
    const int blk  = blockIdx.x;
    const int b    = blk & 7;
    const int rest = blk >> 3;
    const int yt   = rest >> 3;
    const int xh   = rest & 7;
    #pragma unroll
    for (int k = 0; k < 10; ++k)
        *(f32x4*)(lds + tid * 16 + k * 8192) = f32x4{0.f, 0.f, 0.f, 0.f};
    const int lane = tid & 63;
    const int wv   = tid >> 6;
    const int ut   = wv & 1;
    const int yrh  = wv >> 1;
    const int ln   = lane & 15;
    const int qd   = lane >> 4;
    const int offA0 = IN1_OFF + ((2 * yrh) * 16 + ln) * 64 + swz16(qd, ln);
    const int pB    = 16 * ut + ln;
    const int offB  = IN2_OFF + ((2 * yrh) * 32 + pB) * 64 + swz16(qd, pB);
    const float* in1b = in1 + (size_t)b * CHW_;
    const float* in2b = in2 + (size_t)b * CHW_;
    const int pp2 = tid & 7;
    const int g2  = (tid >> 3) & 3;
    const int r2i = tid >> 5;
    const int px2 = 4 * pp2;
    const int gx2 = xh * 16 - 8 + px2;
    const int ry2 = yt * 8 - 4 + r2i;
    const bool valid2 = (gx2 >= 0) && (gx2 <= 124) && (ry2 >= 0) && (ry2 < H_);
    const int slot2 = r2i * 32 + px2;
    const float* sp2base = in2b + (size_t)(8 * g2) * HW_ + ry2 * W_ + gx2;
    const int pq1 = tid & 3;
    const int jj1 = (tid >> 2) & 3;
    const int g1  = (tid >> 4) & 3;
    const int r1i = tid >> 6;
    const int px1 = 4 * pq1;
    const int gx1 = xh * 16 + px1;
    const int y1  = yt * 8 + r1i;
    const int slot1 = r1i * 16 + px1;
    const float* sp1base = in1b + (size_t)(8 * g1 + 2 * jj1) * HW_ + y1 * W_ + gx1;
    f32x4 r2[8], r1v[2];
    auto issue = [&](int kc) {
        const size_t ch = (size_t)kc * 32 * HW_;
        if (valid2) {
            #pragma unroll
            for (int j = 0; j < 8; ++j)
                r2[j] = *(const f32x4*)(sp2base + ch + (size_t)j * HW_);
        }
        r1v[0] = *(const f32x4*)(sp1base + ch);
        r1v[1] = *(const f32x4*)(sp1base + ch + HW_);
    };
    auto store = [&](char* __restrict__ buf) {
        if (valid2) {
            #pragma unroll
            for (int p = 0; p < 4; ++p) {
                union { __hip_bfloat162 h2[4]; short8 s8; } u;
                #pragma unroll
                for (int jj = 0; jj < 4; ++jj)
                    u.h2[jj] = __float22bfloat162_rn(float2{r2[2 * jj][p], r2[2 * jj + 1][p]});
                *(short8*)(buf + IN2_OFF + (slot2 + p) * 64 + swz16(g2, slot2 + p)) = u.s8;
            }
        }
        #pragma unroll
        for (int p = 0; p < 4; ++p) {
            __hip_bfloat162 h = __float22bfloat162_rn(float2{r1v[0][p], r1v[1][p]});
            *(__hip_bfloat162*)(buf + IN1_OFF + (slot1 + p) * 64 + swz16(g1, slot1 + p) + 4 * jj1) = h;
        }
    };
    f32x4 acc0[9], acc1[9];
    #pragma unroll
    for (int s = 0; s < 9; ++s) { acc0[s] = f32x4{0.f,0.f,0.f,0.f}; acc1[s] = f32x4{0.f,0.f,0.f,0.f}; }
    __syncthreads();
    issue(0);
    for (int kc = 0; kc < 8; ++kc) {
        char* buf = lds + (kc & 1) * BUFSZ;
        store(buf);
        if (kc < 7) issue(kc + 1);
        asm volatile("s_waitcnt lgkmcnt(0)" ::: "memory");
        __builtin_amdgcn_s_barrier();
        asm volatile("" ::: "memory");
        short8 a0  = *(const short8*)(buf + offA0);
        short8 a1  = *(const short8*)(buf + offA0 + 16 * 64);
        short8 blo = *(const short8*)(buf + offB);
        #pragma unroll
        for (int s = 0; s < 9; ++s) {
            short8 bhi = *(const short8*)(buf + offB + (s + 1) * IN2_ROWB);
            acc0[s] = __builtin_amdgcn_mfma_f32_16x16x32_bf16(a0, blo, acc0[s], 0, 0, 0);
            acc1[s] = __builtin_amdgcn_mfma_f32_16x16x32_bf16(a1, bhi, acc1[s], 0, 0, 0);
            blo = bhi;
        }
    }
    __syncthreads();
    const float scale = 1.0f / 256.0f;
    float* outb = out + (size_t)b * 81 * HW_ + (size_t)(yt * 8) * W_ + xh * 16;
    #pragma unroll
    for (int s = 0; s < 9; ++s) {
        #pragma unroll
        for (int yr = 0; yr < 2; ++yr) {
            const f32x4 a = yr ? acc1[s] : acc0[s];
            const int y = 2 * yrh + yr;
            #pragma unroll
            for (int r = 0; r < 4; ++r) {
                const int m  = qd * 4 + r;
                const int dx = ln - m - 8 + 16 * ut;
                if (dx >= -4 && dx <= 4)
                    *(float*)(lds + ((y * 9 + dx + 4) * 16 + m) * 4) = a[r] * scale;
            }
        }
        asm volatile("s_waitcnt lgkmcnt(0)" ::: "memory");
        __builtin_amdgcn_s_barrier();
        asm volatile("" ::: "memory");
        #pragma unroll
        for (int i = 0; i < 3; ++i) {
            const int pidx = i * 4 + qd;
            if (pidx < 9) {
                const float v = *(const float*)(lds + ((wv * 9 + pidx) * 16 + ln) * 4);
                outb[((size_t)(s * 9 + pidx) * H_ + wv) * W_ + ln] = v;
            }
        }
        asm volatile("s_waitcnt lgkmcnt(0)" ::: "memory");
        __builtin_amdgcn_s_barrier();
        asm volatile("" ::: "memory");
    }
}

extern "C" void kernel_launch(void* const* d_in, const int* in_sizes, int n_in,
                              void* d_out, int out_size, void* d_ws, size_t ws_size,
                              hipStream_t stream) {
    const float* in1 = (const float*)d_in[0];
    const float* in2 = (const float*)d_in[1];
    float* out = (float*)d_out;

    if (ws_size >= WS_NEED && d_ws != nullptr) {
        prep<<<1536, 256, 0, stream>>>(in1, in2, (char*)d_ws);
        corr_mfma7<<<768, 512, 0, stream>>>((const char*)d_ws, out);
    } else {
        corr_fb<<<768, 512, 0, stream>>>(in1, in2, out);
    }
}

// Round 8
// 308.680 us; speedup vs baseline: 1.0275x; 1.0275x over previous
//
#include <hip/hip_runtime.h>
#include <hip/hip_bf16.h>

// FlowNetC correlation via bf16 MFMA band-GEMM.
// out[b, (dy+4)*9+(dx+4), y, x] = (1/256) * sum_c in1[b,c,y,x] * in2[b,c,y+dy,x+dx]
// B=8, C=256, H=96, W=128, MD=4.
//
// v8 (resubmission — round 7 bench was a GPU-acquisition timeout, kernel
// never ran; source unchanged): dy-split for occupancy. Evidence through v6:
// one 8-wave block/CU (acc 72 AGPR + 100 arch VGPR -> 2 waves/SIMD), every
// pipe <10% busy, ~10.5k cycles/chunk vs ~5k of accountable work ->
// latency-bound with no co-resident block to overlap; per-wave ILP (v6's
// 2-deep bank pipeline) moved nothing. Fix: each block now computes only 3
// of the 9 dy values (grid x3 = 2304 blocks of 512). acc: 72 -> 24 regs;
// staging: one 8-float4 unit per thread (32 regs/bank). Total ~113 regs ->
// fits the 128-reg tier (__launch_bounds__(512,4)) -> TWO independent
// blocks/CU (LDS 2x28 KB/block = 112 KB/CU), overlapping stage<->compute
// phases, while keeping the 2-deep A/B bank load pipeline and the coalesced
// LDS-transpose epilogue. in2 re-staging across dy-groups is L2-served
// (XCD pinning keeps one batch's 3.1 MB chunk-planes in the 4 MB XCD L2).
//
// Block = (b, 8-row y-tile, 16-px x-eighth, dy-group of 3), 512 threads.
// LDS/buffer: in1 8x16 slots + in2 10x32 slots, 64 B/slot = 28 KB; x2 buf.
// Waves: 0-4 stage in2, 5-6 stage in1, 7 none; all compute (ut=wv&1,
// yrh=wv>>1).

#define B_ 8
#define C_ 256
#define H_ 96
#define W_ 128
#define HW_ 12288
#define CHW_ 3145728

#define BUFSZ 28672
#define IN1_OFF 0            // in1: 8*16 = 128 slots (8 KB)
#define IN2_OFF 8192         // in2: 10*32 = 320 slots (20 KB)
#define IN2_ROWB (32 * 64)   // bytes per in2 LDS row

typedef __attribute__((ext_vector_type(8))) short short8;
typedef __attribute__((ext_vector_type(4))) float f32x4;

// bank swizzle on the 16B channel-group within a 64B pixel slot
__device__ __forceinline__ int swz16(int g, int slot) {
    return (g ^ (slot & 3) ^ ((slot >> 2) & 3)) * 16;
}

__global__ __launch_bounds__(512, 4) void corr_mfma8(
    const float* __restrict__ in1,
    const float* __restrict__ in2,
    float* __restrict__ out)
{
    __shared__ __align__(16) char lds[2 * BUFSZ];

    const int tid = threadIdx.x;

    // XCD swizzle: blk%8 -> XCD; each XCD owns one batch image.
    const int blk  = blockIdx.x;
    const int b    = blk & 7;
    const int rest = blk >> 3;        // 0..287
    const int dg   = rest % 3;        // dy-group: dy in {3dg-4, 3dg-3, 3dg-2}
    const int t    = rest / 3;        // 0..95
    const int yt   = t >> 3;          // 0..11 (8-row tiles)
    const int xh   = t & 7;           // 0..7  (16-px eighths)

    // zero both buffers once: halo/OOB slots stay zero for every chunk
    #pragma unroll
    for (int k = 0; k < 7; ++k)
        *(f32x4*)(lds + tid * 16 + k * 8192) = f32x4{0.f, 0.f, 0.f, 0.f};

    // ---- compute ids ----
    const int lane = tid & 63;
    const int wv   = tid >> 6;              // 0..7
    const int ut   = wv & 1;
    const int yrh  = wv >> 1;               // 0..3 -> y rows 2*yrh, 2*yrh+1
    const int ln   = lane & 15;
    const int qd   = lane >> 4;

    const int offA0 = IN1_OFF + ((2 * yrh) * 16 + ln) * 64 + swz16(qd, ln);
    const int pB    = 16 * ut + ln;                          // in2 slot px (0..31)
    const int offB  = IN2_OFF + ((2 * yrh) * 32 + pB) * 64 + swz16(qd, pB);

    const float* in1b = in1 + (size_t)b * CHW_;
    const float* in2b = in2 + (size_t)b * CHW_;

    // ---- staging roles (chunk-invariant) ----
    // in2: tid 0..319 -> unit (r=tid>>5 in 0..9, pxq=(tid>>2)&7, g=tid&3):
    //      8 ch x 4 px at (ry2, gx2). in1: tid 320..447 -> unit (r,pxq,g).
    // wave 7 (tid>=448) stages nothing. All units: 8 float4 loads, 4x16B writes.
    const bool isB = tid < 320;
    const int r_   = isB ? (tid >> 5) : ((tid - 320) >> 4);
    const int pxq  = isB ? ((tid >> 2) & 7) : ((tid >> 2) & 3);
    const int g_   = tid & 3;
    const int gx   = isB ? (xh * 16 - 8 + 4 * pxq) : (xh * 16 + 4 * pxq);
    const int gy   = isB ? (yt * 8 - 4 + 3 * dg + r_) : (yt * 8 + r_);
    const bool vld = isB ? (gx >= 0 && gx <= 124 && gy >= 0 && gy < H_)
                         : (tid < 448);
    const int slot = isB ? (r_ * 32 + 4 * pxq) : (r_ * 16 + 4 * pxq);
    const int goff = isB ? IN2_OFF : IN1_OFF;
    const float* spbase = (isB ? in2b : in1b) + (size_t)(8 * g_) * HW_ + gy * W_ + gx;

    // ---- two independent register banks (static names) ----
    f32x4 rA[8], rB[8];

    auto issueA = [&](int kc) {
        const size_t ch = (size_t)kc * 32 * HW_;
        if (vld) {
            #pragma unroll
            for (int j = 0; j < 8; ++j)
                rA[j] = *(const f32x4*)(spbase + ch + (size_t)j * HW_);
        }
    };
    auto issueB = [&](int kc) {
        const size_t ch = (size_t)kc * 32 * HW_;
        if (vld) {
            #pragma unroll
            for (int j = 0; j < 8; ++j)
                rB[j] = *(const f32x4*)(spbase + ch + (size_t)j * HW_);
        }
    };
    auto storeA = [&](char* __restrict__ buf) {
        if (vld) {
            #pragma unroll
            for (int p = 0; p < 4; ++p) {
                union { __hip_bfloat162 h2[4]; short8 s8; } u;
                #pragma unroll
                for (int jj = 0; jj < 4; ++jj)
                    u.h2[jj] = __float22bfloat162_rn(float2{rA[2 * jj][p], rA[2 * jj + 1][p]});
                *(short8*)(buf + goff + (slot + p) * 64 + swz16(g_, slot + p)) = u.s8;
            }
        }
    };
    auto storeB = [&](char* __restrict__ buf) {
        if (vld) {
            #pragma unroll
            for (int p = 0; p < 4; ++p) {
                union { __hip_bfloat162 h2[4]; short8 s8; } u;
                #pragma unroll
                for (int jj = 0; jj < 4; ++jj)
                    u.h2[jj] = __float22bfloat162_rn(float2{rB[2 * jj][p], rB[2 * jj + 1][p]});
                *(short8*)(buf + goff + (slot + p) * 64 + swz16(g_, slot + p)) = u.s8;
            }
        }
    };

    f32x4 acc0[3], acc1[3];
    #pragma unroll
    for (int s = 0; s < 3; ++s) { acc0[s] = f32x4{0.f,0.f,0.f,0.f}; acc1[s] = f32x4{0.f,0.f,0.f,0.f}; }

    // per-chunk MFMA: 3 dy values; LDS row (2yrh+s) pairs with output row
    // 2yrh at dy=3dg-4+s, row (2yrh+s+1) with output row 2yrh+1.
    auto compute = [&](const char* __restrict__ buf) {
        short8 a0  = *(const short8*)(buf + offA0);
        short8 a1  = *(const short8*)(buf + offA0 + 16 * 64);
        short8 blo = *(const short8*)(buf + offB);
        #pragma unroll
        for (int s = 0; s < 3; ++s) {
            short8 bhi = *(const short8*)(buf + offB + (s + 1) * IN2_ROWB);
            acc0[s] = __builtin_amdgcn_mfma_f32_16x16x32_bf16(a0, blo, acc0[s], 0, 0, 0);
            acc1[s] = __builtin_amdgcn_mfma_f32_16x16x32_bf16(a1, bhi, acc1[s], 0, 0, 0);
            blo = bhi;
        }
    };

    __syncthreads();   // zero-fill visible (no loads in flight yet)

    issueA(0);         // bank A: even chunks -> buf0
    issueB(1);         // bank B: odd chunks  -> buf1

    #pragma unroll
    for (int k2 = 0; k2 < 4; ++k2) {
        // ---- A phase: chunk 2*k2 ----
        storeA(lds);                       // counted wait on bank A only; B in flight
        if (2 * k2 + 2 < 8) issueA(2 * k2 + 2);
        asm volatile("s_waitcnt lgkmcnt(0)" ::: "memory");   // ds_writes retired
        __builtin_amdgcn_s_barrier();                        // raw: no vmcnt drain
        asm volatile("" ::: "memory");
        compute(lds);
        // ---- B phase: chunk 2*k2+1 ----
        storeB(lds + BUFSZ);               // waits on bank B only; A in flight
        if (2 * k2 + 3 < 8) issueB(2 * k2 + 3);
        asm volatile("s_waitcnt lgkmcnt(0)" ::: "memory");
        __builtin_amdgcn_s_barrier();
        asm volatile("" ::: "memory");
        compute(lds + BUFSZ);
        // barrier between compute(bufX) and next storeX(bufX) is the other
        // phase's barrier; its lgkmcnt(0) also drains these ds_reads.
    }

    // ---------------- epilogue: LDS-transposed coalesced band extraction ----
    // Per dy-phase: scatter into ep[y 0..7][dx 0..8][x 0..15] (4.6 KB at lds
    // base), barrier, wave wv stores row y=wv as 4 contiguous 64 B chunks
    // per instruction.
    __syncthreads();   // all waves done with staging buffers

    const float scale = 1.0f / 256.0f;
    float* outb = out + (size_t)b * 81 * HW_ + (size_t)(yt * 8) * W_ + xh * 16;

    #pragma unroll
    for (int s = 0; s < 3; ++s) {
        const int sf = 3 * dg + s;         // channel row block: (dy+4) = sf
        #pragma unroll
        for (int yr = 0; yr < 2; ++yr) {
            const f32x4 a = yr ? acc1[s] : acc0[s];
            const int y = 2 * yrh + yr;
            #pragma unroll
            for (int r = 0; r < 4; ++r) {
                const int m  = qd * 4 + r;
                const int dx = ln - m - 8 + 16 * ut;
                if (dx >= -4 && dx <= 4)
                    *(float*)(lds + ((y * 9 + dx + 4) * 16 + m) * 4) = a[r] * scale;
            }
        }
        asm volatile("s_waitcnt lgkmcnt(0)" ::: "memory");
        __builtin_amdgcn_s_barrier();
        asm volatile("" ::: "memory");
        #pragma unroll
        for (int i = 0; i < 3; ++i) {
            const int pidx = i * 4 + qd;   // dx index 0..11, valid < 9
            if (pidx < 9) {
                const float v = *(const float*)(lds + ((wv * 9 + pidx) * 16 + ln) * 4);
                outb[((size_t)(sf * 9 + pidx) * H_ + wv) * W_ + ln] = v;
            }
        }
        asm volatile("s_waitcnt lgkmcnt(0)" ::: "memory");   // reads done -> ep reusable
        __builtin_amdgcn_s_barrier();                        // stores stay in flight
        asm volatile("" ::: "memory");
    }
}

extern "C" void kernel_launch(void* const* d_in, const int* in_sizes, int n_in,
                              void* d_out, int out_size, void* d_ws, size_t ws_size,
                              hipStream_t stream) {
    const float* in1 = (const float*)d_in[0];
    const float* in2 = (const float*)d_in[1];
    float* out = (float*)d_out;

    // 8 b x (12 y-tiles x 8 x-eighths x 3 dy-groups) = 2304 blocks of 512
    corr_mfma8<<<2304, 512, 0, stream>>>(in1, in2, out);
}